// Round 4
// baseline (841.538 us; speedup 1.0000x reference)
//
#include <hip/hip_runtime.h>
#include <hip/hip_bf16.h>

typedef __hip_bfloat16 bf16;
typedef unsigned short u16;
typedef unsigned int u32;
typedef __attribute__((ext_vector_type(8))) short s8b;     // 8 bf16 = 4 VGPR MFMA frag
typedef __attribute__((ext_vector_type(16))) float f32x16; // 32x32 MFMA accum
typedef __attribute__((ext_vector_type(4))) float f32x4v;
typedef __attribute__((ext_vector_type(4))) u32 u32x4;

#define EPSF 1e-8f
#define STG 907  // staging row stride (899 + 8 pad); keeps float4 maps 16B-aligned

// ---------------------------------------------------------------------------
// Static device buffers:
//   g_wpack : non-fc dense weights, bf16 hi/lo 32x32x16 B-fragments.
//   g_fcpack: fc' = diag(sigma_img)*fcw, per-batch (2 copies), same layout.
//   g_bias  : dense biases (896 f32). fc biases folded into g_fcC.
//   g_fcS   : [2][448] colsum(W')        (AdaIN fold)
//   g_fcC   : [2][448] imean@W' + fcb    (AdaIN fold)
//   g_T*    : images transposed to (b,y,x,c) f32.
// ---------------------------------------------------------------------------
__device__ __align__(16) u16 g_wpack[256000];   // 500 chunks * 512 u16
__device__ __align__(16) u16 g_fcpack[344064];  // 672 chunks
__device__ float g_bias[896];
__device__ float g_fcS[896];
__device__ float g_fcC[896];
__device__ float g_T0[2 * 64 * 64 * 64];
__device__ float g_T1[2 * 128 * 32 * 32];
__device__ float g_T2[2 * 256 * 16 * 16];

// ---- scalar helpers -------------------------------------------------------
__device__ __forceinline__ float ldf(const void* p, size_t i, int f32v) {
  return f32v ? ((const float*)p)[i] : __bfloat162float(((const bf16*)p)[i]);
}
template <bool F32>
__device__ __forceinline__ float ld(const void* p, size_t i) {
  if constexpr (F32) return ((const float*)p)[i];
  else return __bfloat162float(((const bf16*)p)[i]);
}
__device__ __forceinline__ int detect_f32(const void* extr) {
  float v = ((const float*)extr)[0];
  return (fabsf(v - 1.0f) < 0.25f) ? 1 : 0;
}

// hi/lo bf16 split: v ~= hi + lo, ~2^-16 relative error
__device__ __forceinline__ void splitbf(float v, u16& h, u16& l) {
  bf16 hb = __float2bfloat16(v);
  float hf = __bfloat162float(hb);
  bf16 lb = __float2bfloat16(v - hf);
  h = __builtin_bit_cast(u16, hb);
  l = __builtin_bit_cast(u16, lb);
}
__device__ __forceinline__ float bfjoin(u16 h, u16 l) {
  return __uint_as_float((u32)h << 16) + __uint_as_float((u32)l << 16);
}
__device__ __forceinline__ u16 f2bfu(float v) {
  return __builtin_bit_cast(u16, __float2bfloat16(v));
}

// LDS activation tile [32][256] bf16, row stride 512B, XOR swizzle.
__device__ __forceinline__ u16* xaddr(u16* base, int row, int col) {
  int byte = (row << 9) + (col << 1);
  byte ^= (row & 7) << 4;
  return (u16*)((char*)base + byte);
}
__device__ __forceinline__ const u16* xaddrc(const u16* base, int row, int col) {
  int byte = (row << 9) + (col << 1);
  byte ^= (row & 7) << 4;
  return (const u16*)((const char*)base + byte);
}

__device__ __forceinline__ f32x16 MFMA32(s8b a, s8b b, f32x16 c) {
  return __builtin_amdgcn_mfma_f32_32x32x16_bf16(a, b, c, 0, 0, 0);
}

// ---------------------------------------------------------------------------
// prep1: stats + P matrices + LDS-tiled image transposes + weight/bias pack
// ---------------------------------------------------------------------------
template <bool F32>
__device__ void stats_body(const void* img0, const void* img1, const void* img2,
                           const void* intr, const void* extr,
                           float* wsf, float* red) {
  int bid = blockIdx.x;
  if (bid >= 896) {
    int b = bid - 896;
    int t = threadIdx.x;
    if (t < 12) {
      int r = t >> 2, c = t & 3;
      float acc = 0.f;
      for (int k = 0; k < 3; ++k)
        acc += ld<F32>(intr, b * 9 + r * 3 + k) * ld<F32>(extr, b * 12 + k * 4 + c);
      wsf[b * 12 + r * 4 + c] = acc;
    }
    return;
  }
  const void* src; size_t base; int HW, outidx;
  if (bid < 128) {
    int b = bid >> 6, c = bid & 63;
    src = img0; base = (size_t)(b * 64 + c) * 4096; HW = 4096;
    outidx = 32 + b * 64 + c;
  } else if (bid < 384) {
    int t = bid - 128; int b = t >> 7, c = t & 127;
    src = img1; base = (size_t)(b * 128 + c) * 1024; HW = 1024;
    outidx = 32 + 128 + b * 128 + c;
  } else {
    int t = bid - 384; int b = t >> 8, c = t & 255;
    src = img2; base = (size_t)(b * 256 + c) * 256; HW = 256;
    outidx = 32 + 384 + b * 256 + c;
  }
  float s1 = 0.f, s2 = 0.f;
  for (int i = threadIdx.x; i < HW; i += 256) {
    float v = ld<F32>(src, base + i);
    s1 += v; s2 += v * v;
  }
  for (int off = 32; off; off >>= 1) {
    s1 += __shfl_xor(s1, off);
    s2 += __shfl_xor(s2, off);
  }
  int wid = threadIdx.x >> 6, lane = threadIdx.x & 63;
  if (lane == 0) { red[wid] = s1; red[4 + wid] = s2; }
  __syncthreads();
  if (threadIdx.x == 0) {
    float S1 = red[0] + red[1] + red[2] + red[3];
    float S2 = red[4] + red[5] + red[6] + red[7];
    float mu = S1 / (float)HW;
    float var = (S2 - (float)HW * mu * mu) / (float)(HW - 1);
    var = fmaxf(var, 0.f);
    wsf[outidx] = mu;
    wsf[outidx + 896] = sqrtf(var + EPSF);
  }
}

__global__ __launch_bounds__(256) void prep1(
    const void* img0, const void* img1, const void* img2,
    const void* intr, const void* extr,
    const void* w1_0, const void* w2_0, const void* w1_1, const void* w2_1,
    const void* w1_2, const void* w2_2,
    const void* b1_0, const void* b2_0, const void* b1_1, const void* b2_1,
    const void* b1_2, const void* b2_2,
    float* wsf) {
  __shared__ float red[8];
  __shared__ float tl[4352];  // up to 256*(16+1)
  const int f32v = detect_f32(extr);
  int bid = blockIdx.x;
  int tid = threadIdx.x;

  if (bid < 898) {
    if (f32v) stats_body<true>(img0, img1, img2, intr, extr, wsf, red);
    else      stats_body<false>(img0, img1, img2, intr, extr, wsf, red);
    return;
  }
  if (bid < 1122) {  // LDS-tiled transposes, one (b,y) plane per block
    int pl = bid - 898;
    const void* src; float* dst; int C, R, rsh, csh, b, y;
    if (pl < 128)      { src = img0; dst = g_T0; C = 64;  R = 64; rsh = 6; csh = 6; b = pl >> 6; y = pl & 63; }
    else if (pl < 192) { src = img1; dst = g_T1; C = 128; R = 32; rsh = 5; csh = 7; int q = pl - 128; b = q >> 5; y = q & 31; }
    else               { src = img2; dst = g_T2; C = 256; R = 16; rsh = 4; csh = 8; int q = pl - 192; b = q >> 4; y = q & 15; }
    int CR = C * R;
    for (int i = tid; i < CR; i += 256) {  // coalesced-ish read (full lines)
      int c = i >> rsh, x = i & (R - 1);
      tl[c * (R + 1) + x] = ldf(src, ((size_t)(b * C + c) * R + y) * R + x, f32v);
    }
    __syncthreads();
    for (int i = tid; i < CR; i += 256) {  // fully coalesced write
      int x = i >> csh, c = i & (C - 1);
      dst[((size_t)(b * R + y) * R + x) * C + c] = tl[c * (R + 1) + x];
    }
    return;
  }
  if (bid < 1247) {  // non-fc weight pack: 500 chunks
    int chunk = (bid - 1122) * 4 + (tid >> 6);
    int lane = tid & 63;
    if (chunk < 500) {
      const int cbase[6] = {0, 4, 20, 52, 116, 244};
      const int couts[6] = {64, 64, 128, 128, 256, 256};
      const int kreal[6] = {3, 64, 64, 128, 128, 256};
      const void* wp[6] = {w1_0, w2_0, w1_1, w2_1, w1_2, w2_2};
      int layer = 5;
      for (int s = 0; s < 5; ++s) if (chunk < cbase[s + 1]) { layer = s; break; }
      int ci = chunk - cbase[layer];
      int COUT = couts[layer], KR = kreal[layer];
      int STR = COUT >> 5;
      int ks = ci / (STR * 2);
      int rem = ci % (STR * 2);
      int nt = rem >> 1, split = rem & 1;
      const void* W = wp[layer];
      s8b sv;
#pragma unroll
      for (int j = 0; j < 8; ++j) {
        int k = ks * 16 + 8 * (lane >> 5) + j;
        int c = nt * 32 + (lane & 31);
        float v = (k < KR) ? ldf(W, (size_t)k * COUT + c, f32v) : 0.f;
        u16 h, l; splitbf(v, h, l);
        sv[j] = (short)(split == 0 ? h : l);
      }
      *(s8b*)((char*)g_wpack + (size_t)chunk * 1024 + lane * 16) = sv;
    }
    return;
  }
  {  // bias pack: 896 values
    int t = (bid - 1247) * 256 + tid;
    if (t < 896) {
      const int off[7] = {0, 64, 128, 256, 384, 640, 896};
      const void* bp[6] = {b1_0, b2_0, b1_1, b2_1, b1_2, b2_2};
      int seg = 0;
      while (seg < 5 && t >= off[seg + 1]) ++seg;
      g_bias[t] = ldf(bp[seg], t - off[seg], f32v);
    }
  }
}

// ---------------------------------------------------------------------------
// prep2: fc' = diag(sigma)*fcw pack (per batch) + S/cvec fold vectors.
// ---------------------------------------------------------------------------
__global__ __launch_bounds__(256) void prep2(
    const void* extr,
    const void* fcw_0, const void* fcw_1, const void* fcw_2,
    const void* fcb_0, const void* fcb_1, const void* fcb_2,
    const float* wsf) {
  const int f32v = detect_f32(extr);
  int bid = blockIdx.x;
  int tid = threadIdx.x;
  if (bid < 168) {  // 672 fc chunks
    int chunk = bid * 4 + (tid >> 6);
    int lane = tid & 63;
    int bb = chunk / 336;
    int ci = chunk % 336;
    int C, COUT, loff; const void* W;
    if (ci < 16)      { C = 64;  COUT = 64;  loff = 0;   W = fcw_0; }
    else if (ci < 80) { C = 128; COUT = 128; loff = 128; W = fcw_1; ci -= 16; }
    else              { C = 256; COUT = 256; loff = 384; W = fcw_2; ci -= 80; }
    int STR = COUT >> 5;
    int ks = ci / (STR * 2);
    int rem = ci % (STR * 2);
    int nt = rem >> 1, split = rem & 1;
    const float* sig = wsf + 928 + loff + bb * C;
    s8b sv;
#pragma unroll
    for (int j = 0; j < 8; ++j) {
      int k = ks * 16 + 8 * (lane >> 5) + j;
      int c = nt * 32 + (lane & 31);
      float v = sig[k] * ldf(W, (size_t)k * COUT + c, f32v);
      u16 h, l; splitbf(v, h, l);
      sv[j] = (short)(split == 0 ? h : l);
    }
    *(s8b*)((char*)g_fcpack + (size_t)chunk * 1024 + lane * 16) = sv;
    return;
  }
  {  // S/cvec: 6 blocks
    int idx = bid - 168;
    if (idx >= 6) return;
    int bb = idx / 3, layer = idx % 3;
    int C, colbase, loff; const void* W; const void* fb;
    if (layer == 0)      { C = 64;  colbase = 0;   loff = 0;   W = fcw_0; fb = fcb_0; }
    else if (layer == 1) { C = 128; colbase = 64;  loff = 128; W = fcw_1; fb = fcb_1; }
    else                 { C = 256; colbase = 192; loff = 384; W = fcw_2; fb = fcb_2; }
    int j = tid;
    if (j >= C) return;
    const float* sig = wsf + 928 + loff + bb * C;
    const float* mean = wsf + 32 + loff + bb * C;
    float S = 0.f, Cv = 0.f;
    for (int c = 0; c < C; ++c) {
      float w = sig[c] * ldf(W, (size_t)c * C + j, f32v);
      S += w;
      Cv += mean[c] * w;
    }
    Cv += ldf(fb, j, f32v);
    g_fcS[bb * 448 + colbase + j] = S;
    g_fcC[bb * 448 + colbase + j] = Cv;
  }
}

// ---------------------------------------------------------------------------
// MFMA core: acc[NTW] (32x32 tiles) = X[32 x KS*16] @ W (+bias), hi/lo 3-MFMA
// ---------------------------------------------------------------------------
template <int KS, int COUT, int NTW, bool HASBIAS>
__device__ __forceinline__ void mm32(
    const u16* Xh_, const u16* Xl_, const char* wlane,
    const float* biasp, int nt0, int lane, f32x16* acc) {
#pragma unroll
  for (int n = 0; n < NTW; ++n) {
    float bv = HASBIAS ? biasp[(nt0 + n) * 32 + (lane & 31)] : 0.f;
#pragma unroll
    for (int q = 0; q < 16; ++q) acc[n][q] = bv;
  }
  const int rowA = lane & 31;
  const int acol = (lane >> 5) * 8;
#pragma unroll
  for (int ks = 0; ks < KS; ++ks) {
    s8b ah = *(const s8b*)xaddrc(Xh_, rowA, ks * 16 + acol);
    s8b al = *(const s8b*)xaddrc(Xl_, rowA, ks * 16 + acol);
#pragma unroll
    for (int n = 0; n < NTW; ++n) {
      const char* ch = wlane + (size_t)((ks * (COUT / 32) + nt0 + n) * 2) * 1024;
      s8b bh = *(const s8b*)(ch);
      s8b bl = *(const s8b*)(ch + 1024);
      acc[n] = MFMA32(ah, bh, acc[n]);
      acc[n] = MFMA32(ah, bl, acc[n]);
      acc[n] = MFMA32(al, bh, acc[n]);
    }
  }
}

// dense layer, in-place (mm -> sync -> writeback -> sync)
template <int KS, int COUT>
__device__ __forceinline__ void dense32(u16* Xh_, u16* Xl_,
                                        int wbyte, int bbase, int tid) {
  constexpr int NTW = (COUT == 256) ? 2 : 1;
  int lane = tid & 63, wid = tid >> 6;
  int nt0, active;
  if constexpr (COUT == 64)      { nt0 = (wid & 1);  active = (wid < 2); }
  else if constexpr (COUT == 128){ nt0 = wid;        active = 1; }
  else                           { nt0 = wid * 2;    active = 1; }
  f32x16 acc[NTW];
  if (active)
    mm32<KS, COUT, NTW, true>(Xh_, Xl_,
        (const char*)g_wpack + wbyte + lane * 16, g_bias + bbase, nt0, lane, acc);
  __syncthreads();
  if (active) {
    int g = lane >> 5;
#pragma unroll
    for (int n = 0; n < NTW; ++n) {
      int col = (nt0 + n) * 32 + (lane & 31);
#pragma unroll
      for (int q = 0; q < 16; ++q) {
        int row = (q & 3) + 8 * (q >> 2) + 4 * g;
        float v = fmaxf(acc[n][q], 0.f);
        u16 h, l; splitbf(v, h, l);
        *xaddr(Xh_, row, col) = h;
        *xaddr(Xl_, row, col) = l;
      }
    }
  }
  __syncthreads();
}

// per-row mean / inv-std over C (ddof=1), read-only on X
template <int C>
__device__ __forceinline__ void musig(const u16* Xh_, const u16* Xl_,
                                      int lane, float& mu, float& rs) {
  int row = lane & 31;
  int c0 = (lane >> 5) * (C / 2);
  float s1 = 0.f, s2 = 0.f;
#pragma unroll
  for (int k = 0; k < C / 2; k += 8) {
    s8b h = *(const s8b*)xaddrc(Xh_, row, c0 + k);
    s8b l = *(const s8b*)xaddrc(Xl_, row, c0 + k);
#pragma unroll
    for (int i = 0; i < 8; ++i) {
      float f = bfjoin((u16)h[i], (u16)l[i]);
      s1 += f; s2 += f * f;
    }
  }
  s1 += __shfl_xor(s1, 32);
  s2 += __shfl_xor(s2, 32);
  mu = s1 / (float)C;
  float var = (s2 - (float)C * mu * mu) / (float)(C - 1);
  var = fmaxf(var, 0.f);
  rs = 1.0f / sqrtf(var + EPSF);
}

// ---- bilinear border sample into LDS staging ------------------------------
template <int C, int R>
__device__ __forceinline__ void sample_stg(
    const float* T, float u, float v, int b, int lane, float* stg) {
  constexpr int J = C / 64;
  float ix = fminf(fmaxf((u + 1.f) * 0.5f * (float)(R - 1), 0.f), (float)(R - 1));
  float iy = fminf(fmaxf((v + 1.f) * 0.5f * (float)(R - 1), 0.f), (float)(R - 1));
  float x0f = floorf(ix), y0f = floorf(iy);
  float wx = ix - x0f, wy = iy - y0f;
  int x0 = (int)x0f, y0 = (int)y0f;
  int x1 = min(x0 + 1, R - 1), y1 = min(y0 + 1, R - 1);
  float w00 = (1.f - wx) * (1.f - wy), w01 = wx * (1.f - wy);
  float w10 = (1.f - wx) * wy,         w11 = wx * wy;
  const float* T00 = T + (size_t)((b * R + y0) * R + x0) * C;
  const float* T01 = T + (size_t)((b * R + y0) * R + x1) * C;
  const float* T10 = T + (size_t)((b * R + y1) * R + x0) * C;
  const float* T11 = T + (size_t)((b * R + y1) * R + x1) * C;
#pragma unroll
  for (int j = 0; j < J; ++j) {
    int c = lane + 64 * j;
    stg[c] = T00[c] * w00 + T01[c] * w01 + T10[c] * w10 + T11[c] * w11;
  }
}

// ---------------------------------------------------------------------------
// Main fused kernel: 32 points/block, 4 waves, 32x32x16 MFMA.
// fc accumulators held in registers; after fc2 the LDS activation buffer is
// reused as an 8-row x STG-col f32 staging tile; each output row is written
// exactly once via contiguous vectorized nontemporal stores. Staging rows
// carry an 8-col pad duplicating the next row's cols 0-7 so aligned float4
// flush reads are linear across row boundaries.
// ---------------------------------------------------------------------------
__global__ __launch_bounds__(256, 4) void pce_main(
    const void* init_pc, const void* extr, const float* wsf, void* out) {
  __shared__ __align__(16) u16 Xsh[16384];  // Xh = [0,8192), Xl = [8192,16384)
  u16* Xh = Xsh;
  u16* Xl = Xsh + 8192;
  const int f32v = detect_f32(extr);
  const int tid = threadIdx.x;
  const int lane = tid & 63;
  const int wid = tid >> 6;
  const int hi = lane >> 5;
  const int colc = lane & 31;
  const u32 R0 = blockIdx.x * 32;
  const int b = (int)(R0 >> 16);

  // zero K-pad region (cols 0..15, all rows), stage pc into cols 0..2
  for (int i = tid; i < 512; i += 256) {
    int r = i >> 4, c = i & 15;
    *xaddr(Xh, r, c) = 0;
    *xaddr(Xl, r, c) = 0;
  }
  __syncthreads();
  if (tid < 96) {
    int r = tid / 3, c = tid % 3;
    float v = ldf(init_pc, (size_t)(R0 + r) * 3 + c, f32v);
    u16 h, l; splitbf(v, h, l);
    *xaddr(Xh, r, c) = h;
    *xaddr(Xl, r, c) = l;
  }
  __syncthreads();

  float mu0, rs0, mu1, rs1, mu2, rs2;
  f32x16 a0[1], a1[1], a2[2];

  // ---- block 0 (64ch) ----
  dense32<1, 64>(Xh, Xl, 0, 0, tid);
  dense32<4, 64>(Xh, Xl, 4096, 64, tid);
  musig<64>(Xh, Xl, lane, mu0, rs0);
  if (wid < 2)
    mm32<4, 64, 1, false>(Xh, Xl,
        (const char*)g_fcpack + b * 344064 + 0 + lane * 16, nullptr, wid & 1, lane, a0);

  // ---- block 1 (128ch) ---- (fc reads precede next dense's first sync)
  dense32<4, 128>(Xh, Xl, 20480, 128, tid);
  dense32<8, 128>(Xh, Xl, 53248, 256, tid);
  musig<128>(Xh, Xl, lane, mu1, rs1);
  mm32<8, 128, 1, false>(Xh, Xl,
      (const char*)g_fcpack + b * 344064 + 16384 + lane * 16, nullptr, wid, lane, a1);

  // ---- block 2 (256ch) ----
  dense32<8, 256>(Xh, Xl, 118784, 384, tid);
  dense32<16, 256>(Xh, Xl, 249856, 640, tid);
  musig<256>(Xh, Xl, lane, mu2, rs2);
  mm32<16, 256, 2, false>(Xh, Xl,
      (const char*)g_fcpack + b * 344064 + 81920 + lane * 16, nullptr, wid * 2, lane, a2);

  __syncthreads();  // all LDS activation reads done; Xsh reusable as staging

  // preload per-wave fold constants and P matrix
  const int scb = b * 448;
  float S0 = 0.f, C0 = 0.f;
  if (wid < 2) { S0 = g_fcS[scb + wid * 32 + colc]; C0 = g_fcC[scb + wid * 32 + colc]; }
  float S1 = g_fcS[scb + 64 + wid * 32 + colc];
  float C1 = g_fcC[scb + 64 + wid * 32 + colc];
  float S2a = g_fcS[scb + 192 + wid * 64 + colc];
  float C2a = g_fcC[scb + 192 + wid * 64 + colc];
  float S2b = g_fcS[scb + 192 + wid * 64 + 32 + colc];
  float C2b = g_fcC[scb + 192 + wid * 64 + 32 + colc];
  float Pm[12];
#pragma unroll
  for (int i = 0; i < 12; ++i) Pm[i] = wsf[b * 12 + i];

  float* stg = (float*)Xsh;  // [8][STG] f32 staging

#pragma unroll
  for (int g = 0; g < 4; ++g) {
    // --- fc deposits: q = 4g+qq -> local row qq + 4*hi ---
#pragma unroll
    for (int qq = 0; qq < 4; ++qq) {
      int q = 4 * g + qq;
      int lr = qq + 4 * hi;          // local row in group (0..7)
      int trow = 8 * g + lr;         // tile row (0..31) for mu/rs shfl
      float m0 = __shfl(mu0, trow), r0v = __shfl(rs0, trow);
      float m1 = __shfl(mu1, trow), r1v = __shfl(rs1, trow);
      float m2 = __shfl(mu2, trow), r2v = __shfl(rs2, trow);
      if (wid < 2) {
        float v0 = r0v * (a0[0][q] - m0 * S0) + C0;
        stg[lr * STG + wid * 32 + colc] = v0;
        // duplicate next-row cols 0..7 into previous row's pad slots
        if (wid == 0 && colc < 8 && lr > 0)
          stg[(lr - 1) * STG + 899 + colc] = v0;
      }
      stg[lr * STG + 64 + wid * 32 + colc] = r1v * (a1[0][q] - m1 * S1) + C1;
      stg[lr * STG + 192 + wid * 64 + colc] = r2v * (a2[0][q] - m2 * S2a) + C2a;
      stg[lr * STG + 192 + wid * 64 + 32 + colc] = r2v * (a2[1][q] - m2 * S2b) + C2b;
    }
    // --- projection deposits: wave handles local rows 2*wid, 2*wid+1 ---
#pragma unroll
    for (int pp = 0; pp < 2; ++pp) {
      int lr = wid * 2 + pp;
      u32 n = R0 + 8 * g + lr;
      float px = ldf(init_pc, (size_t)n * 3 + 0, f32v);
      float py = ldf(init_pc, (size_t)n * 3 + 1, f32v);
      float pz = ldf(init_pc, (size_t)n * 3 + 2, f32v);
      float X = Pm[0] * px + Pm[1] * py + Pm[2] * pz + Pm[3];
      float Y = Pm[4] * px + Pm[5] * py + Pm[6] * pz + Pm[7];
      float Z = Pm[8] * px + Pm[9] * py + Pm[10] * pz + Pm[11];
      float u = -X / Z, vv = Y / Z;
      float* srow = stg + lr * STG;
      sample_stg<64, 64>(g_T0, u, vv, b, lane, srow + 448);
      sample_stg<128, 32>(g_T1, u, vv, b, lane, srow + 512);
      sample_stg<256, 16>(g_T2, u, vv, b, lane, srow + 640);
      if (lane < 3) srow[896 + lane] = (lane == 0) ? px : (lane == 1) ? py : pz;
    }
    __syncthreads();
    // --- flush 8 complete rows, contiguous, vectorized, nontemporal ---
    u32 base = (R0 + 8 * g) * 899u;
    if (f32v) {
      float* op = (float*)out + base;
      for (int i = tid; i < 1798; i += 256) {
        u32 e = (u32)i * 4u;
        u32 r = e / 899u;
        f32x4v v = *(const f32x4v*)(stg + e + 8u * r);
        __builtin_nontemporal_store(v, (f32x4v*)(op + e));
      }
    } else {
      u32* op = (u32*)out + (base >> 1);
      for (int i = tid; i < 899; i += 256) {
        u32 e = (u32)i * 8u;
        u32 r = e / 899u;
        const float* s = stg + e + 8u * r;
        f32x4v va = *(const f32x4v*)(s);
        f32x4v vb = *(const f32x4v*)(s + 4);
        u32x4 pk;
        pk.x = (u32)f2bfu(va.x) | ((u32)f2bfu(va.y) << 16);
        pk.y = (u32)f2bfu(va.z) | ((u32)f2bfu(va.w) << 16);
        pk.z = (u32)f2bfu(vb.x) | ((u32)f2bfu(vb.y) << 16);
        pk.w = (u32)f2bfu(vb.z) | ((u32)f2bfu(vb.w) << 16);
        __builtin_nontemporal_store(pk, (u32x4*)(op + (size_t)i * 4));
      }
    }
    __syncthreads();
  }
}

// ---------------------------------------------------------------------------
extern "C" void kernel_launch(void* const* d_in, const int* in_sizes, int n_in,
                              void* d_out, int out_size, void* d_ws, size_t ws_size,
                              hipStream_t stream) {
  const void* init_pc = d_in[0];
  const void* extr    = d_in[1];
  const void* intr    = d_in[2];
  const void* img0    = d_in[3];
  const void* img1    = d_in[4];
  const void* img2    = d_in[5];
  const void* w1_0 = d_in[6],  *b1_0 = d_in[7];
  const void* w2_0 = d_in[8],  *b2_0 = d_in[9];
  const void* fcw_0 = d_in[10], *fcb_0 = d_in[11];
  const void* w1_1 = d_in[12], *b1_1 = d_in[13];
  const void* w2_1 = d_in[14], *b2_1 = d_in[15];
  const void* fcw_1 = d_in[16], *fcb_1 = d_in[17];
  const void* w1_2 = d_in[18], *b1_2 = d_in[19];
  const void* w2_2 = d_in[20], *b2_2 = d_in[21];
  const void* fcw_2 = d_in[22], *fcb_2 = d_in[23];

  float* wsf = (float*)d_ws;

  // prep1: stats(898) | transpose(224) | wpack(125) | bias(4)
  prep1<<<1251, 256, 0, stream>>>(
      img0, img1, img2, intr, extr,
      w1_0, w2_0, w1_1, w2_1, w1_2, w2_2,
      b1_0, b2_0, b1_1, b2_1, b1_2, b2_2, wsf);
  // prep2: fc' pack (168) + S/cvec (6); needs stats
  prep2<<<174, 256, 0, stream>>>(
      extr, fcw_0, fcw_1, fcw_2, fcb_0, fcb_1, fcb_2, wsf);
  pce_main<<<4096, 256, 0, stream>>>(init_pc, extr, wsf, d_out);
}